// Round 4
// baseline (4778.971 us; speedup 1.0000x reference)
//
#include <hip/hip_runtime.h>
#include <hip/hip_bf16.h>
#include <cmath>

// All float tensors are f32 (per reference: jnp.float32). Output f32 [64].
// Problem constants: B=32, S=64, T=64, E=512, H=512, 4H=2048, V=32000

__device__ __forceinline__ float sigf(float x){ return 1.0f/(1.0f+__expf(-x)); }

// ---------------- workspace layout (float offsets), ~22.5 MB ----------------
constexpr long o_senc   = 0;                     // [B][S][1024]
constexpr long o_satt   = o_senc + 32L*64*1024;  // [B][S][512]
constexpr long o_aves   = o_satt + 32L*64*512;   // [T*B][512]
constexpr long o_hF     = o_aves + 64L*32*512;   // zero-block start
constexpr long o_cF     = o_hF + 32L*512;
constexpr long o_hB     = o_cF + 32L*512;
constexpr long o_cB     = o_hB + 32L*512;
constexpr long o_sumexp = o_cB + 32L*512;        // 2048 (zero block = 67584 floats)
constexpr long o_gold   = o_sumexp + 2048;
constexpr long o_ccat   = o_gold + 2048;         // [32][1024]
constexpr long o_dech   = o_ccat + 32L*1024;
constexpr long o_decc   = o_dech + 32L*512;
constexpr long o_att    = o_decc + 32L*512;
constexpr long o_ctx    = o_att + 32L*512;       // [32][1024]
constexpr long o_gatesP = o_ctx + 32L*1024;      // [16][32][2048] chunk stride 65536
constexpr long o_attvP  = o_gatesP + 16L*65536;  // [12][32][512]

// ---------------- utility ----------------
__global__ void k_zero(float* p, int n){
    int i = blockIdx.x*256 + threadIdx.x;
    if (i < n) p[i] = 0.f;
}

// ---------------- split-K gates tile helpers ----------------
// P[b*ldp + n0+nl] = sum_{k<128} A[b][k0+k] * W[(n0+nl)*ldw + kw + k]
__device__ __forceinline__ void gt_mac_store(const float (*Hs)[128], const float (*Ws)[129],
                                             float* __restrict__ P, int ldp, int n0){
    __syncthreads();
    int tid = threadIdx.x;
    int nl = tid & 63, bg = tid >> 6;
    float acc[8] = {};
    for (int k=0;k<128;++k){
        float w = Ws[nl][k];
        #pragma unroll
        for (int i=0;i<8;++i) acc[i] += Hs[bg*8+i][k] * w;
    }
    #pragma unroll
    for (int i=0;i<8;++i)
        P[(long)(bg*8+i)*ldp + n0 + nl] = acc[i];
}

__device__ __forceinline__ void gt_load_W(const float* __restrict__ W, int ldw, int kw, int n0,
                                          float (*Ws)[129]){
    int tid = threadIdx.x;
    int nl = tid >> 2, kl = (tid & 3) * 32;   // 64 rows x 128 cols, 32 floats/thread
    const float* wp = W + (long)(n0+nl)*ldw + kw + kl;
    #pragma unroll
    for (int i=0;i<32;i+=4){
        float4 v = *(const float4*)(wp + i);
        Ws[nl][kl+i+0]=v.x; Ws[nl][kl+i+1]=v.y; Ws[nl][kl+i+2]=v.z; Ws[nl][kl+i+3]=v.w;
    }
}

// A from f32 scratch (32 x lda)
__device__ __forceinline__ void gates_tile_f32(
    const float* __restrict__ A, int lda, int k0,
    const float* __restrict__ W, int ldw, int kw, int n0,
    float* __restrict__ P, int ldp, float (*Hs)[128], float (*Ws)[129]){
    int tid = threadIdx.x;
    int bl = tid >> 3, kl = (tid & 7) * 16;   // 32 rows x 128 cols, 16/thread
    const float* ap = A + (long)bl*lda + k0 + kl;
    float* hp = &Hs[bl][kl];
    #pragma unroll
    for (int i=0;i<16;i+=4){
        float4 v = *(const float4*)(ap + i);
        hp[i+0]=v.x; hp[i+1]=v.y; hp[i+2]=v.z; hp[i+3]=v.w;
    }
    gt_load_W(W, ldw, kw, n0, Ws);
    gt_mac_store(Hs, Ws, P, ldp, n0);
}

// A gathered from embedding table: row bl -> emb[tok[off + bl*stride]][k0..]
__device__ __forceinline__ void gates_tile_emb(
    const float* __restrict__ emb, const int* __restrict__ tok, int off, int stride, int k0,
    const float* __restrict__ W, int ldw, int kw, int n0,
    float* __restrict__ P, int ldp, float (*Hs)[128], float (*Ws)[129]){
    int tid = threadIdx.x;
    int bl = tid >> 3, kl = (tid & 7) * 16;
    const float* ap = emb + (long)tok[off + bl*stride]*512 + k0 + kl;
    float* hp = &Hs[bl][kl];
    #pragma unroll
    for (int i=0;i<16;i+=4){
        float4 v = *(const float4*)(ap + i);
        hp[i+0]=v.x; hp[i+1]=v.y; hp[i+2]=v.z; hp[i+3]=v.w;
    }
    gt_load_W(W, ldw, kw, n0, Ws);
    gt_mac_store(Hs, Ws, P, ldp, n0);
}

// ---------------- encoder ----------------
// 512 blocks: dir(2) x kc(8) x nc(32). kc<4: x-part (emb) vs Wih; kc>=4: h-part vs Whh.
__global__ __launch_bounds__(256)
void k_enc_gates(const int* __restrict__ tok, const float* __restrict__ emb,
                 const float* __restrict__ hF, const float* __restrict__ hB,
                 const float* __restrict__ WihF, const float* __restrict__ WhhF,
                 const float* __restrict__ WihB, const float* __restrict__ WhhB,
                 float* __restrict__ gatesP, int s){
    __shared__ float Hs[32][128];
    __shared__ float Ws[64][129];
    int bx = blockIdx.x;
    int dir = bx >> 8, rem = bx & 255;
    int kc = rem & 7, nc = rem >> 3;
    int sd = dir ? 63 - s : s;
    float* P = gatesP + (long)(dir*8 + kc)*65536;
    if (kc < 4)
        gates_tile_emb(emb, tok, sd*32, 1, kc*128,
                       dir ? WihB : WihF, 512, kc*128, nc*64, P, 2048, Hs, Ws);
    else
        gates_tile_f32(dir ? hB : hF, 512, (kc-4)*128,
                       dir ? WhhB : WhhF, 512, (kc-4)*128, nc*64, P, 2048, Hs, Ws);
}

__global__ void k_enc_cell(const float* __restrict__ gatesP,
                           const float* __restrict__ bF, const float* __restrict__ bB,
                           float* hF, float* cF, float* hB, float* cB,
                           float* __restrict__ senc, const int* __restrict__ lens, int s){
    int idx = blockIdx.x*256 + threadIdx.x;  // 2*32*512
    int dir = idx >> 14, r = idx & 16383;
    int b = r >> 9, j = r & 511;
    int sd = dir ? (63 - s) : s;
    const float* P = gatesP + (long)dir*8*65536;
    const float* bias = dir ? bB : bF;
    float g[4];
    #pragma unroll
    for (int gi=0; gi<4; ++gi){
        int n = j + gi*512;
        float v = bias[n];
        #pragma unroll
        for (int kc=0; kc<8; ++kc) v += P[(long)kc*65536 + b*2048 + n];
        g[gi] = v;
    }
    float* hPtr = dir ? hB : hF;
    float* cPtr = dir ? cB : cF;
    float ho = hPtr[b*512+j], co = cPtr[b*512+j];
    float cn = sigf(g[1])*co + sigf(g[0])*tanhf(g[2]);
    float hn = sigf(g[3])*tanhf(cn);
    bool valid = sd < lens[b];
    hPtr[b*512+j] = valid ? hn : ho;
    cPtr[b*512+j] = valid ? cn : co;
    senc[(long)(b*64+sd)*1024 + dir*512 + j] = valid ? hn : 0.f;
}

__global__ void k_ccat(const float* __restrict__ cF, const float* __restrict__ cB,
                       float* __restrict__ ccat){
    int idx = blockIdx.x*256 + threadIdx.x;   // 32*1024
    int b = idx >> 10, d = idx & 1023;
    ccat[idx] = (d < 512) ? cF[b*512+d] : cB[b*512+d-512];
}

// ---------------- generic tiled GEMM: C[m,n] = sum_k A[m,k]*W[n,k] (+bias) ----------------
__global__ __launch_bounds__(256)
void k_gemm(const float* __restrict__ A, const float* __restrict__ W,
            const float* __restrict__ bias, float* __restrict__ C,
            int M, int K, int lda, int ldw, int ldc){
    __shared__ float As[16][65];
    __shared__ float Wt[16][65];
    int tid = threadIdx.x;
    int m0 = blockIdx.x * 64, n0 = blockIdx.y * 64;
    int ty = tid >> 4, tx = tid & 15;
    int lm = tid >> 2, lk = (tid & 3) * 4;
    float acc[4][4] = {};
    for (int kt = 0; kt < K; kt += 16){
        float4 av;
        if (m0 + lm < M) av = *(const float4*)(A + (long)(m0+lm)*lda + kt + lk);
        else av = make_float4(0.f,0.f,0.f,0.f);
        As[lk+0][lm]=av.x; As[lk+1][lm]=av.y; As[lk+2][lm]=av.z; As[lk+3][lm]=av.w;
        float4 wv = *(const float4*)(W + (long)(n0+lm)*ldw + kt + lk);
        Wt[lk+0][lm]=wv.x; Wt[lk+1][lm]=wv.y; Wt[lk+2][lm]=wv.z; Wt[lk+3][lm]=wv.w;
        __syncthreads();
        #pragma unroll
        for (int k = 0; k < 16; ++k){
            float a0=As[k][ty*4+0], a1=As[k][ty*4+1], a2=As[k][ty*4+2], a3=As[k][ty*4+3];
            float b0=Wt[k][tx*4+0], b1=Wt[k][tx*4+1], b2=Wt[k][tx*4+2], b3=Wt[k][tx*4+3];
            acc[0][0]+=a0*b0; acc[0][1]+=a0*b1; acc[0][2]+=a0*b2; acc[0][3]+=a0*b3;
            acc[1][0]+=a1*b0; acc[1][1]+=a1*b1; acc[1][2]+=a1*b2; acc[1][3]+=a1*b3;
            acc[2][0]+=a2*b0; acc[2][1]+=a2*b1; acc[2][2]+=a2*b2; acc[2][3]+=a2*b3;
            acc[3][0]+=a3*b0; acc[3][1]+=a3*b1; acc[3][2]+=a3*b2; acc[3][3]+=a3*b3;
        }
        __syncthreads();
    }
    #pragma unroll
    for (int i=0;i<4;++i){
        int m = m0 + ty*4 + i;
        if (m >= M) continue;
        #pragma unroll
        for (int j=0;j<4;++j){
            int n = n0 + tx*4 + j;
            float v = acc[i][j];
            if (bias) v += bias[n];
            C[(long)m*ldc + n] = v;
        }
    }
}

__global__ void k_dec_init(const float* __restrict__ decc0, float* dech, float* att){
    int idx = blockIdx.x*256 + threadIdx.x;   // 16384
    dech[idx] = tanhf(decc0[idx]);
    att[idx] = 0.f;
}

// ---------------- decoder ----------------
// 384 blocks: kc(12) x nc(32). kc<4: y-part (emb); kc4..7: att-part; kc8..11: h-part.
__global__ __launch_bounds__(256)
void k_dec_gates(const int* __restrict__ tok, const float* __restrict__ emb,
                 const float* __restrict__ att, const float* __restrict__ dech,
                 const float* __restrict__ Wih, const float* __restrict__ Whh,
                 float* __restrict__ gatesP, int t){
    __shared__ float Hs[32][128];
    __shared__ float Ws[64][129];
    int bx = blockIdx.x;
    int kc = bx % 12, nc = bx / 12;
    float* P = gatesP + (long)kc*65536;
    if (kc < 4)
        gates_tile_emb(emb, tok, t, 64, kc*128, Wih, 1024, kc*128, nc*64, P, 2048, Hs, Ws);
    else if (kc < 8)
        gates_tile_f32(att, 512, (kc-4)*128, Wih, 1024, 512 + (kc-4)*128, nc*64, P, 2048, Hs, Ws);
    else
        gates_tile_f32(dech, 512, (kc-8)*128, Whh, 512, (kc-8)*128, nc*64, P, 2048, Hs, Ws);
}

__global__ __launch_bounds__(256)
void k_dec_attn(const float* __restrict__ gatesP, const float* __restrict__ db,
                float* dech, float* decc,
                const float* __restrict__ satt, const float* __restrict__ senc,
                const int* __restrict__ lens, float* __restrict__ ctx){
    __shared__ float hS[512];
    __shared__ float scoreP[64][5];
    __shared__ float alphaS[64];
    int b = blockIdx.x, tid = threadIdx.x;
    // phase A: LSTM cell (2 hidden units / thread)
    #pragma unroll
    for (int jj=0; jj<2; ++jj){
        int j = tid + jj*256;
        float g[4];
        #pragma unroll
        for (int gi=0; gi<4; ++gi){
            int n = j + gi*512;
            float v = db[n];
            #pragma unroll
            for (int kc=0; kc<12; ++kc) v += gatesP[(long)kc*65536 + b*2048 + n];
            g[gi] = v;
        }
        float c = sigf(g[1])*decc[b*512+j] + sigf(g[0])*tanhf(g[2]);
        float h = sigf(g[3])*tanhf(c);
        decc[b*512+j] = c; dech[b*512+j] = h; hS[j] = h;
    }
    __syncthreads();
    // phase B: scores + softmax
    {
        int si = tid >> 2, q = tid & 3;
        const float* sa = satt + (long)(b*64+si)*512 + q*128;
        float p = 0.f;
        for (int k=0;k<128;++k) p += sa[k]*hS[q*128+k];
        scoreP[si][q] = p;
    }
    __syncthreads();
    if (tid < 64){
        float sc = scoreP[tid][0]+scoreP[tid][1]+scoreP[tid][2]+scoreP[tid][3];
        if (tid >= lens[b]) sc = -INFINITY;
        float mx = sc;
        #pragma unroll
        for (int o=32;o>0;o>>=1) mx = fmaxf(mx, __shfl_xor(mx, o));
        float e = (sc == -INFINITY) ? 0.f : __expf(sc - mx);
        float sm = e;
        #pragma unroll
        for (int o=32;o>0;o>>=1) sm += __shfl_xor(sm, o);
        alphaS[tid] = e / fmaxf(sm, 1e-30f);
    }
    __syncthreads();
    // phase C: context (4 dims / thread)
    float4 acc = make_float4(0.f,0.f,0.f,0.f);
    const float* sb = senc + (long)b*64*1024 + tid*4;
    for (int s2=0;s2<64;++s2){
        float a = alphaS[s2];
        float4 v = *(const float4*)(sb + s2*1024);
        acc.x += a*v.x; acc.y += a*v.y; acc.z += a*v.z; acc.w += a*v.w;
    }
    *(float4*)(ctx + b*1024 + tid*4) = acc;
}

// 96 blocks: kc(12) x nc(8). kc<4: h-part; kc>=4: ctx-part.
__global__ __launch_bounds__(256)
void k_attvec(const float* __restrict__ dech, const float* __restrict__ ctx,
              const float* __restrict__ Wv, float* __restrict__ attvP){
    __shared__ float Hs[32][128];
    __shared__ float Ws[64][129];
    int bx = blockIdx.x;
    int kc = bx % 12, nc = bx / 12;
    float* P = attvP + (long)kc*16384;
    if (kc < 4)
        gates_tile_f32(dech, 512, kc*128, Wv, 1536, kc*128, nc*64, P, 512, Hs, Ws);
    else
        gates_tile_f32(ctx, 1024, (kc-4)*128, Wv, 1536, 512 + (kc-4)*128, nc*64, P, 512, Hs, Ws);
}

__global__ void k_attvec_fin(const float* __restrict__ attvP, float* att,
                             float* aves, int t){
    int idx = blockIdx.x*256 + threadIdx.x;   // 16384
    int b = idx >> 9, j = idx & 511;
    float v = 0.f;
    #pragma unroll
    for (int kc=0; kc<12; ++kc) v += attvP[(long)kc*16384 + b*512 + j];
    v = tanhf(v);
    att[idx] = v;
    aves[(long)(t*32+b)*512 + j] = v;
}

// ---------------- readout GEMM with fused exp-sum epilogue ----------------
__global__ __launch_bounds__(256)
void k_readout(const float* __restrict__ A, const float* __restrict__ W,
               float* __restrict__ sumexp){
    __shared__ float As[16][65];
    __shared__ float Wt[16][65];
    __shared__ float red[64][17];
    int tid = threadIdx.x;
    int m0 = blockIdx.x * 64, n0 = blockIdx.y * 64;
    int ty = tid >> 4, tx = tid & 15;
    int lm = tid >> 2, lk = (tid & 3) * 4;
    float acc[4][4] = {};
    for (int kt = 0; kt < 512; kt += 16){
        float4 av = *(const float4*)(A + (long)(m0+lm)*512 + kt + lk);
        As[lk+0][lm]=av.x; As[lk+1][lm]=av.y; As[lk+2][lm]=av.z; As[lk+3][lm]=av.w;
        float4 wv = *(const float4*)(W + (long)(n0+lm)*512 + kt + lk);
        Wt[lk+0][lm]=wv.x; Wt[lk+1][lm]=wv.y; Wt[lk+2][lm]=wv.z; Wt[lk+3][lm]=wv.w;
        __syncthreads();
        #pragma unroll
        for (int k = 0; k < 16; ++k){
            float a0=As[k][ty*4+0], a1=As[k][ty*4+1], a2=As[k][ty*4+2], a3=As[k][ty*4+3];
            float b0=Wt[k][tx*4+0], b1=Wt[k][tx*4+1], b2=Wt[k][tx*4+2], b3=Wt[k][tx*4+3];
            acc[0][0]+=a0*b0; acc[0][1]+=a0*b1; acc[0][2]+=a0*b2; acc[0][3]+=a0*b3;
            acc[1][0]+=a1*b0; acc[1][1]+=a1*b1; acc[1][2]+=a1*b2; acc[1][3]+=a1*b3;
            acc[2][0]+=a2*b0; acc[2][1]+=a2*b1; acc[2][2]+=a2*b2; acc[2][3]+=a2*b3;
            acc[3][0]+=a3*b0; acc[3][1]+=a3*b1; acc[3][2]+=a3*b2; acc[3][3]+=a3*b3;
        }
        __syncthreads();
    }
    #pragma unroll
    for (int i=0;i<4;++i){
        float rs = 0.f;
        #pragma unroll
        for (int j=0;j<4;++j) rs += __expf(acc[i][j]);
        red[ty*4+i][tx] = rs;
    }
    __syncthreads();
    if (tid < 64){
        float s = 0.f;
        #pragma unroll
        for (int x=0;x<16;++x) s += red[tid][x];
        atomicAdd(&sumexp[m0+tid], s);
    }
}

// ---------------- gold + final ----------------
__global__ void k_gold(const float* __restrict__ aves, const float* __restrict__ Wr,
                       const int* __restrict__ tgt, float* __restrict__ gold){
    int wid = threadIdx.x >> 6, lane = threadIdx.x & 63;
    int m = blockIdx.x*4 + wid;   // m = t*32 + b
    int t = m >> 5, b = m & 31;
    int g = tgt[b*64 + t];
    const float* arow = aves + (long)m*512;
    const float* wrow = Wr + (long)g*512;
    float p = 0.f;
    for (int k=lane; k<512; k+=64) p += arow[k]*wrow[k];
    #pragma unroll
    for (int o=32;o>0;o>>=1) p += __shfl_xor(p, o);
    if (lane == 0) gold[m] = p;
}

__global__ void k_final(const float* __restrict__ gold, const float* __restrict__ sumexp,
                        const int* __restrict__ tgt, float* __restrict__ out){
    int t = threadIdx.x;  // 64 threads
    float a = 0.f;
    for (int b=0;b<32;++b){
        int m = t*32 + b;
        float lp = gold[m] - logf(fmaxf(sumexp[m], 1e-30f));
        if (tgt[b*64 + t] != 0) a += lp;
    }
    out[t] = a;
}

// ---------------- launch ----------------
extern "C" void kernel_launch(void* const* d_in, const int* in_sizes, int n_in,
                              void* d_out, int out_size, void* d_ws, size_t ws_size,
                              hipStream_t stream){
    const int* src_tok   = (const int*)d_in[0];
    const int* tgt_tok   = (const int*)d_in[1];
    const int* lens      = (const int*)d_in[2];
    const float* src_emb = (const float*)d_in[3];
    const float* tgt_emb = (const float*)d_in[4];
    const float* eWihF   = (const float*)d_in[5];
    const float* eWhhF   = (const float*)d_in[6];
    const float* ebF     = (const float*)d_in[7];
    const float* eWihB   = (const float*)d_in[8];
    const float* eWhhB   = (const float*)d_in[9];
    const float* ebB     = (const float*)d_in[10];
    const float* dWih    = (const float*)d_in[11];
    const float* dWhh    = (const float*)d_in[12];
    const float* db      = (const float*)d_in[13];
    const float* Wasrc   = (const float*)d_in[14];
    const float* Wavec   = (const float*)d_in[15];
    const float* Wread   = (const float*)d_in[16];
    const float* Winit   = (const float*)d_in[17];
    const float* binit   = (const float*)d_in[18];
    float* ws  = (float*)d_ws;
    float* out = (float*)d_out;

    float* senc = ws + o_senc;  float* satt = ws + o_satt; float* aves = ws + o_aves;
    float* hF = ws + o_hF; float* cF = ws + o_cF; float* hB = ws + o_hB; float* cB = ws + o_cB;
    float* sumexp = ws + o_sumexp; float* gold = ws + o_gold;
    float* ccat = ws + o_ccat;
    float* dech = ws + o_dech; float* decc = ws + o_decc; float* att = ws + o_att;
    float* ctx = ws + o_ctx;
    float* gatesP = ws + o_gatesP; float* attvP = ws + o_attvP;

    // zero states + sumexp (contiguous 67584 floats at o_hF)
    k_zero<<<264, 256, 0, stream>>>(hF, 67584);

    // encoder recurrence
    for (int s = 0; s < 64; ++s){
        k_enc_gates<<<512, 256, 0, stream>>>(src_tok, src_emb, hF, hB,
                                             eWihF, eWhhF, eWihB, eWhhB, gatesP, s);
        k_enc_cell<<<128, 256, 0, stream>>>(gatesP, ebF, ebB, hF, cF, hB, cB, senc, lens, s);
    }

    // [c_f|c_b]; src_att; decoder init
    k_ccat<<<128, 256, 0, stream>>>(cF, cB, ccat);
    k_gemm<<<dim3(32,8), 256, 0, stream>>>(senc, Wasrc, nullptr, satt, 2048, 1024, 1024, 1024, 512);
    k_gemm<<<dim3(1,8), 256, 0, stream>>>(ccat, Winit, binit, decc, 32, 1024, 1024, 1024, 512);
    k_dec_init<<<64, 256, 0, stream>>>(decc, dech, att);

    // decoder recurrence
    for (int t = 0; t < 64; ++t){
        k_dec_gates<<<384, 256, 0, stream>>>(tgt_tok, tgt_emb, att, dech, dWih, dWhh, gatesP, t);
        k_dec_attn<<<32, 256, 0, stream>>>(gatesP, db, dech, decc, satt, senc, lens, ctx);
        k_attvec<<<96, 256, 0, stream>>>(dech, ctx, Wavec, attvP);
        k_attvec_fin<<<64, 256, 0, stream>>>(attvP, att, aves, t);
    }

    // readout: sumexp + gold + final
    k_readout<<<dim3(32,500), 256, 0, stream>>>(aves, Wread, sumexp);
    k_gold<<<512, 256, 0, stream>>>(aves, Wread, tgt_tok, gold);
    k_final<<<1, 64, 0, stream>>>(gold, sumexp, tgt_tok, out);
}

// Round 5
// 4559.389 us; speedup vs baseline: 1.0482x; 1.0482x over previous
//
#include <hip/hip_runtime.h>
#include <hip/hip_bf16.h>
#include <cmath>

// All float tensors f32 (reference: jnp.float32). Output f32 [64].
// B=32, S=64, T=64, E=512, H=512, 4H=2048, V=32000

__device__ __forceinline__ float sigf(float x){ return 1.0f/(1.0f+__expf(-x)); }
__device__ __forceinline__ short f2bf(float x){
    unsigned u = __builtin_bit_cast(unsigned, x);
    u += 0x7fff + ((u >> 16) & 1);
    return (short)(u >> 16);
}

typedef __attribute__((ext_vector_type(8))) short short8;   // 8 bf16 (4 VGPR)
typedef __attribute__((ext_vector_type(4))) float float4v;  // 4 f32 acc

// ---------------- workspace (d_ws) layout, proven <=22.5MB ----------------
constexpr long o_senc   = 0;                     // [B][S][1024]
constexpr long o_satt   = o_senc + 32L*64*1024;  // [B][S][512]
constexpr long o_aves   = o_satt + 32L*64*512;   // [T*B][512] f32
constexpr long o_hF     = o_aves + 64L*32*512;   // zero-block start
constexpr long o_cF     = o_hF + 32L*512;
constexpr long o_hB     = o_cF + 32L*512;
constexpr long o_cB     = o_hB + 32L*512;
constexpr long o_sumexp = o_cB + 32L*512;        // 2048 (zero block = 67584 floats)
constexpr long o_gold   = o_sumexp + 2048;
constexpr long o_ccat   = o_gold + 2048;         // [32][1024]
constexpr long o_dech   = o_ccat + 32L*1024;
constexpr long o_decc   = o_dech + 32L*512;
constexpr long o_att    = o_decc + 32L*512;      // (unused now)
constexpr long o_ctx    = o_att + 32L*512;       // [32][1024]
constexpr long o_gatesP = o_ctx + 32L*1024;      // [8][32][2048] stride 65536
constexpr long o_attvP  = o_gatesP + 16L*65536;  // [12][32][512]

// ---------------- static device buffers (independent of ws_size) ----------------
__device__ __align__(16) float g_X[3][2048L*2048];     // Xf, Xb, Yg (raw x-part gates)
__device__ __align__(16) short g_Wread_bf[32000L*512];
__device__ __align__(16) short g_bfA[2][2048L*512];    // srcx_bf, tgty_bf
__device__ __align__(16) short g_bfW[3][2048L*512];    // WihF_bf, WihB_bf, dWihY_bf
__device__ __align__(16) short g_aves_bf[2048L*512];

// ---------------- utility ----------------
__global__ void k_zero(float* p, int n){
    int i = blockIdx.x*256 + threadIdx.x;
    if (i < n) p[i] = 0.f;
}

// f32 [rows][ldin] (first 512 cols) -> bf16 [rows][512]
__global__ void k_cvt(const float* __restrict__ in, short* __restrict__ out, int ldin){
    long idx = (long)blockIdx.x*256 + threadIdx.x;
    long r = idx >> 9; int c = idx & 511;
    out[idx] = f2bf(in[r*ldin + c]);
}

// token gather -> bf16 rows. mode 0: src flat-reshape; mode 1: tgt transpose
__global__ void k_gather_bf(const float* __restrict__ emb, const int* __restrict__ tok,
                            short* __restrict__ out, int mode){
    long idx = (long)blockIdx.x*256 + threadIdx.x;   // 2048*512
    int m = idx >> 9, e = idx & 511;
    int ti = mode ? ((m & 31)*64 + (m >> 5)) : m;
    out[idx] = f2bf(emb[(long)tok[ti]*512 + e]);
}

// ---------------- MFMA bf16 GEMM: C[m,n] = sum_k A[m,k]*B[n,k], K=512 ----------------
// STORE=1: store f32 C (ldc=N). STORE=0: atomicAdd(sumexp[m], sum_n exp(C[m,n])).
template<int STORE>
__global__ __launch_bounds__(256)
void k_mfma_gemm(const short* __restrict__ A, const short* __restrict__ B,
                 float* __restrict__ C, int ldc){
    __shared__ short As[128][72];
    __shared__ short Bs[128][72];
    int tid = threadIdx.x, l = tid & 63, w = tid >> 6;
    int wm = w >> 1, wn = w & 1;
    long m0 = (long)blockIdx.x * 128, n0 = (long)blockIdx.y * 128;
    float4v acc[4][4];
    #pragma unroll
    for (int a=0;a<4;++a)
        #pragma unroll
        for (int b=0;b<4;++b)
            #pragma unroll
            for (int e=0;e<4;++e) acc[a][b][e] = 0.f;

    for (int kb = 0; kb < 8; ++kb){
        #pragma unroll
        for (int i = tid; i < 1024; i += 256){
            int r = i >> 3, c = i & 7;
            *(uint4*)&As[r][c*8] = *(const uint4*)(A + (m0+r)*512 + kb*64 + c*8);
            *(uint4*)&Bs[r][c*8] = *(const uint4*)(B + (n0+r)*512 + kb*64 + c*8);
        }
        __syncthreads();
        #pragma unroll
        for (int ks = 0; ks < 2; ++ks){
            short8 af[4], bf[4];
            #pragma unroll
            for (int tm=0;tm<4;++tm)
                af[tm] = *(const short8*)&As[wm*64 + tm*16 + (l&15)][ks*32 + (l>>4)*8];
            #pragma unroll
            for (int tn=0;tn<4;++tn)
                bf[tn] = *(const short8*)&Bs[wn*64 + tn*16 + (l&15)][ks*32 + (l>>4)*8];
            #pragma unroll
            for (int tm=0;tm<4;++tm)
                #pragma unroll
                for (int tn=0;tn<4;++tn)
                    acc[tm][tn] = __builtin_amdgcn_mfma_f32_16x16x32_bf16(
                        af[tm], bf[tn], acc[tm][tn], 0, 0, 0);
        }
        __syncthreads();
    }

    int q = l >> 4;  // quad group
    if (STORE){
        #pragma unroll
        for (int tm=0;tm<4;++tm)
            #pragma unroll
            for (int r=0;r<4;++r){
                long m = m0 + wm*64 + tm*16 + q*4 + r;
                #pragma unroll
                for (int tn=0;tn<4;++tn)
                    C[m*ldc + n0 + wn*64 + tn*16 + (l&15)] = acc[tm][tn][r];
            }
    } else {
        #pragma unroll
        for (int tm=0;tm<4;++tm)
            #pragma unroll
            for (int r=0;r<4;++r){
                float s = 0.f;
                #pragma unroll
                for (int tn=0;tn<4;++tn) s += __expf(acc[tm][tn][r]);
                s += __shfl_xor(s, 1); s += __shfl_xor(s, 2);
                s += __shfl_xor(s, 4); s += __shfl_xor(s, 8);
                if ((l & 15) == 0)
                    atomicAdd(&C[m0 + wm*64 + tm*16 + q*4 + r], s);
            }
    }
}

// ---------------- split-K gates tile helpers (f32 VALU) ----------------
__device__ __forceinline__ void gt_mac_store(const float (*Hs)[128], const float (*Ws)[129],
                                             float* __restrict__ P, int ldp, int n0){
    __syncthreads();
    int tid = threadIdx.x;
    int nl = tid & 63, bg = tid >> 6;
    float acc[8] = {};
    for (int k=0;k<128;++k){
        float w = Ws[nl][k];
        #pragma unroll
        for (int i=0;i<8;++i) acc[i] += Hs[bg*8+i][k] * w;
    }
    #pragma unroll
    for (int i=0;i<8;++i)
        P[(long)(bg*8+i)*ldp + n0 + nl] = acc[i];
}

__device__ __forceinline__ void gt_load_W(const float* __restrict__ W, int ldw, int kw, int n0,
                                          float (*Ws)[129]){
    int tid = threadIdx.x;
    int nl = tid >> 2, kl = (tid & 3) * 32;
    const float* wp = W + (long)(n0+nl)*ldw + kw + kl;
    #pragma unroll
    for (int i=0;i<32;i+=4){
        float4 v = *(const float4*)(wp + i);
        Ws[nl][kl+i+0]=v.x; Ws[nl][kl+i+1]=v.y; Ws[nl][kl+i+2]=v.z; Ws[nl][kl+i+3]=v.w;
    }
}

__device__ __forceinline__ void gates_tile_f32(
    const float* __restrict__ A, int lda, int k0,
    const float* __restrict__ W, int ldw, int kw, int n0,
    float* __restrict__ P, int ldp, float (*Hs)[128], float (*Ws)[129]){
    int tid = threadIdx.x;
    int bl = tid >> 3, kl = (tid & 7) * 16;
    const float* ap = A + (long)bl*lda + k0 + kl;
    float* hp = &Hs[bl][kl];
    #pragma unroll
    for (int i=0;i<16;i+=4){
        float4 v = *(const float4*)(ap + i);
        hp[i+0]=v.x; hp[i+1]=v.y; hp[i+2]=v.z; hp[i+3]=v.w;
    }
    gt_load_W(W, ldw, kw, n0, Ws);
    gt_mac_store(Hs, Ws, P, ldp, n0);
}

// ---------------- encoder ----------------
// 256 blocks: dir(2) x kc(4) x nc(32), h-part only (x-part precomputed in g_X)
__global__ __launch_bounds__(256)
void k_enc_gates(const float* __restrict__ hF, const float* __restrict__ hB,
                 const float* __restrict__ WhhF, const float* __restrict__ WhhB,
                 float* __restrict__ gatesP){
    __shared__ float Hs[32][128];
    __shared__ float Ws[64][129];
    int bx = blockIdx.x;
    int dir = bx >> 7, rem = bx & 127;
    int kc = rem & 3, nc = rem >> 2;
    float* P = gatesP + (long)(dir*4 + kc)*65536;
    gates_tile_f32(dir ? hB : hF, 512, kc*128,
                   dir ? WhhB : WhhF, 512, kc*128, nc*64, P, 2048, Hs, Ws);
}

__global__ void k_enc_cell(const float* __restrict__ gatesP,
                           const float* __restrict__ bF, const float* __restrict__ bB,
                           float* hF, float* cF, float* hB, float* cB,
                           float* __restrict__ senc, const int* __restrict__ lens, int s){
    int idx = blockIdx.x*256 + threadIdx.x;  // 2*32*512
    int dir = idx >> 14, r = idx & 16383;
    int b = r >> 9, j = r & 511;
    int sd = dir ? (63 - s) : s;
    const float* P = gatesP + (long)dir*4*65536;
    const float* X = g_X[dir];
    const float* bias = dir ? bB : bF;
    float g[4];
    #pragma unroll
    for (int gi=0; gi<4; ++gi){
        int n = j + gi*512;
        float v = bias[n] + X[(long)(sd*32+b)*2048 + n];
        #pragma unroll
        for (int kc=0; kc<4; ++kc) v += P[(long)kc*65536 + b*2048 + n];
        g[gi] = v;
    }
    float* hPtr = dir ? hB : hF;
    float* cPtr = dir ? cB : cF;
    float ho = hPtr[b*512+j], co = cPtr[b*512+j];
    float cn = sigf(g[1])*co + sigf(g[0])*tanhf(g[2]);
    float hn = sigf(g[3])*tanhf(cn);
    bool valid = sd < lens[b];
    hPtr[b*512+j] = valid ? hn : ho;
    cPtr[b*512+j] = valid ? cn : co;
    senc[(long)(b*64+sd)*1024 + dir*512 + j] = valid ? hn : 0.f;
}

__global__ void k_ccat(const float* __restrict__ cF, const float* __restrict__ cB,
                       float* __restrict__ ccat){
    int idx = blockIdx.x*256 + threadIdx.x;   // 32*1024
    int b = idx >> 10, d = idx & 1023;
    ccat[idx] = (d < 512) ? cF[b*512+d] : cB[b*512+d-512];
}

// ---------------- generic f32 tiled GEMM (satt, init) ----------------
__global__ __launch_bounds__(256)
void k_gemm(const float* __restrict__ A, const float* __restrict__ W,
            const float* __restrict__ bias, float* __restrict__ C,
            int M, int K, int lda, int ldw, int ldc){
    __shared__ float As[16][65];
    __shared__ float Wt[16][65];
    int tid = threadIdx.x;
    int m0 = blockIdx.x * 64, n0 = blockIdx.y * 64;
    int ty = tid >> 4, tx = tid & 15;
    int lm = tid >> 2, lk = (tid & 3) * 4;
    float acc[4][4] = {};
    for (int kt = 0; kt < K; kt += 16){
        float4 av;
        if (m0 + lm < M) av = *(const float4*)(A + (long)(m0+lm)*lda + kt + lk);
        else av = make_float4(0.f,0.f,0.f,0.f);
        As[lk+0][lm]=av.x; As[lk+1][lm]=av.y; As[lk+2][lm]=av.z; As[lk+3][lm]=av.w;
        float4 wv = *(const float4*)(W + (long)(n0+lm)*ldw + kt + lk);
        Wt[lk+0][lm]=wv.x; Wt[lk+1][lm]=wv.y; Wt[lk+2][lm]=wv.z; Wt[lk+3][lm]=wv.w;
        __syncthreads();
        #pragma unroll
        for (int k = 0; k < 16; ++k){
            float a0=As[k][ty*4+0], a1=As[k][ty*4+1], a2=As[k][ty*4+2], a3=As[k][ty*4+3];
            float b0=Wt[k][tx*4+0], b1=Wt[k][tx*4+1], b2=Wt[k][tx*4+2], b3=Wt[k][tx*4+3];
            acc[0][0]+=a0*b0; acc[0][1]+=a0*b1; acc[0][2]+=a0*b2; acc[0][3]+=a0*b3;
            acc[1][0]+=a1*b0; acc[1][1]+=a1*b1; acc[1][2]+=a1*b2; acc[1][3]+=a1*b3;
            acc[2][0]+=a2*b0; acc[2][1]+=a2*b1; acc[2][2]+=a2*b2; acc[2][3]+=a2*b3;
            acc[3][0]+=a3*b0; acc[3][1]+=a3*b1; acc[3][2]+=a3*b2; acc[3][3]+=a3*b3;
        }
        __syncthreads();
    }
    #pragma unroll
    for (int i=0;i<4;++i){
        int m = m0 + ty*4 + i;
        if (m >= M) continue;
        #pragma unroll
        for (int j=0;j<4;++j){
            int n = n0 + tx*4 + j;
            float v = acc[i][j];
            if (bias) v += bias[n];
            C[(long)m*ldc + n] = v;
        }
    }
}

__global__ void k_dec_init(const float* __restrict__ decc0, float* dech){
    int idx = blockIdx.x*256 + threadIdx.x;   // 16384
    dech[idx] = tanhf(decc0[idx]);
}

// ---------------- decoder ----------------
// 320 blocks. bx<256: kc=bx&7 (0..3 att-part via inline attvP reduce; 4..7 h-part), nc=bx>>3.
// bx>=256: write aves[t-1] (f32 + bf16) from attvP.
__global__ __launch_bounds__(256)
void k_dec_gates(const float* __restrict__ dech,
                 const float* __restrict__ Wih, const float* __restrict__ Whh,
                 const float* __restrict__ attvP, float* __restrict__ gatesP,
                 float* __restrict__ aves, int t){
    __shared__ float Hs[32][128];
    __shared__ float Ws[64][129];
    int bx = blockIdx.x, tid = threadIdx.x;
    if (bx >= 256){
        if (t == 0) return;
        int idx = (bx-256)*256 + tid;   // 16384
        int b = idx >> 9, j = idx & 511;
        float v = 0.f;
        #pragma unroll
        for (int kc=0; kc<12; ++kc) v += attvP[(long)kc*16384 + b*512 + j];
        v = tanhf(v);
        long m = (long)(t-1)*32 + b;
        aves[m*512 + j] = v;
        g_aves_bf[m*512 + j] = f2bf(v);
        return;
    }
    int kc = bx & 7, nc = bx >> 3;
    float* P = gatesP + (long)kc*65536;
    if (kc < 4){
        // stage att slice [32][kc*128..+128] from attvP (zero at t==0)
        int bl = tid >> 3, kl = (tid & 7) * 16;
        #pragma unroll
        for (int i=0;i<16;++i){
            float v = 0.f;
            if (t > 0){
                int col = kc*128 + kl + i;
                #pragma unroll
                for (int c12=0;c12<12;++c12) v += attvP[(long)c12*16384 + bl*512 + col];
                v = tanhf(v);
            }
            Hs[bl][kl+i] = v;
        }
        gt_load_W(Wih, 1024, 512 + kc*128, nc*64, Ws);
        gt_mac_store(Hs, Ws, P, 2048, nc*64);
    } else {
        gates_tile_f32(dech, 512, (kc-4)*128, Whh, 512, (kc-4)*128, nc*64, P, 2048, Hs, Ws);
    }
}

__global__ __launch_bounds__(256)
void k_dec_attn(const float* __restrict__ gatesP, const float* __restrict__ db,
                float* dech, float* decc,
                const float* __restrict__ satt, const float* __restrict__ senc,
                const int* __restrict__ lens, float* __restrict__ ctx, int t){
    __shared__ float hS[512];
    __shared__ float scoreP[64][5];
    __shared__ float alphaS[64];
    int b = blockIdx.x, tid = threadIdx.x;
    const float* Yg = g_X[2];
    #pragma unroll
    for (int jj=0; jj<2; ++jj){
        int j = tid + jj*256;
        float g[4];
        #pragma unroll
        for (int gi=0; gi<4; ++gi){
            int n = j + gi*512;
            float v = db[n] + Yg[(long)(t*32+b)*2048 + n];
            #pragma unroll
            for (int kc=0; kc<8; ++kc) v += gatesP[(long)kc*65536 + b*2048 + n];
            g[gi] = v;
        }
        float c = sigf(g[1])*decc[b*512+j] + sigf(g[0])*tanhf(g[2]);
        float h = sigf(g[3])*tanhf(c);
        decc[b*512+j] = c; dech[b*512+j] = h; hS[j] = h;
    }
    __syncthreads();
    {
        int si = tid >> 2, q = tid & 3;
        const float* sa = satt + (long)(b*64+si)*512 + q*128;
        float p = 0.f;
        for (int k=0;k<128;++k) p += sa[k]*hS[q*128+k];
        scoreP[si][q] = p;
    }
    __syncthreads();
    if (tid < 64){
        float sc = scoreP[tid][0]+scoreP[tid][1]+scoreP[tid][2]+scoreP[tid][3];
        if (tid >= lens[b]) sc = -INFINITY;
        float mx = sc;
        #pragma unroll
        for (int o=32;o>0;o>>=1) mx = fmaxf(mx, __shfl_xor(mx, o));
        float e = (sc == -INFINITY) ? 0.f : __expf(sc - mx);
        float sm = e;
        #pragma unroll
        for (int o=32;o>0;o>>=1) sm += __shfl_xor(sm, o);
        alphaS[tid] = e / fmaxf(sm, 1e-30f);
    }
    __syncthreads();
    float4 acc = make_float4(0.f,0.f,0.f,0.f);
    const float* sb = senc + (long)b*64*1024 + tid*4;
    for (int s2=0;s2<64;++s2){
        float a = alphaS[s2];
        float4 v = *(const float4*)(sb + s2*1024);
        acc.x += a*v.x; acc.y += a*v.y; acc.z += a*v.z; acc.w += a*v.w;
    }
    *(float4*)(ctx + b*1024 + tid*4) = acc;
}

// 96 blocks: kc(12) x nc(8). kc<4: h-part; kc>=4: ctx-part.
__global__ __launch_bounds__(256)
void k_attvec(const float* __restrict__ dech, const float* __restrict__ ctx,
              const float* __restrict__ Wv, float* __restrict__ attvP){
    __shared__ float Hs[32][128];
    __shared__ float Ws[64][129];
    int bx = blockIdx.x;
    int kc = bx % 12, nc = bx / 12;
    float* P = attvP + (long)kc*16384;
    if (kc < 4)
        gates_tile_f32(dech, 512, kc*128, Wv, 1536, kc*128, nc*64, P, 512, Hs, Ws);
    else
        gates_tile_f32(ctx, 1024, (kc-4)*128, Wv, 1536, 512 + (kc-4)*128, nc*64, P, 512, Hs, Ws);
}

// final aves write (t=63)
__global__ void k_aves_last(const float* __restrict__ attvP, float* __restrict__ aves){
    int idx = blockIdx.x*256 + threadIdx.x;   // 16384
    int b = idx >> 9, j = idx & 511;
    float v = 0.f;
    #pragma unroll
    for (int kc=0; kc<12; ++kc) v += attvP[(long)kc*16384 + b*512 + j];
    v = tanhf(v);
    long m = 63L*32 + b;
    aves[m*512 + j] = v;
    g_aves_bf[m*512 + j] = f2bf(v);
}

// ---------------- gold + final ----------------
__global__ void k_gold(const float* __restrict__ aves, const float* __restrict__ Wr,
                       const int* __restrict__ tgt, float* __restrict__ gold){
    int wid = threadIdx.x >> 6, lane = threadIdx.x & 63;
    int m = blockIdx.x*4 + wid;   // m = t*32 + b
    int t = m >> 5, b = m & 31;
    int g = tgt[b*64 + t];
    const float* arow = aves + (long)m*512;
    const float* wrow = Wr + (long)g*512;
    float p = 0.f;
    for (int k=lane; k<512; k+=64) p += arow[k]*wrow[k];
    #pragma unroll
    for (int o=32;o>0;o>>=1) p += __shfl_xor(p, o);
    if (lane == 0) gold[m] = p;
}

__global__ void k_final(const float* __restrict__ gold, const float* __restrict__ sumexp,
                        const int* __restrict__ tgt, float* __restrict__ out){
    int t = threadIdx.x;
    float a = 0.f;
    for (int b=0;b<32;++b){
        int m = t*32 + b;
        float lp = gold[m] - logf(fmaxf(sumexp[m], 1e-30f));
        if (tgt[b*64 + t] != 0) a += lp;
    }
    out[t] = a;
}

// ---------------- launch ----------------
extern "C" void kernel_launch(void* const* d_in, const int* in_sizes, int n_in,
                              void* d_out, int out_size, void* d_ws, size_t ws_size,
                              hipStream_t stream){
    const int* src_tok   = (const int*)d_in[0];
    const int* tgt_tok   = (const int*)d_in[1];
    const int* lens      = (const int*)d_in[2];
    const float* src_emb = (const float*)d_in[3];
    const float* tgt_emb = (const float*)d_in[4];
    const float* eWihF   = (const float*)d_in[5];
    const float* eWhhF   = (const float*)d_in[6];
    const float* ebF     = (const float*)d_in[7];
    const float* eWihB   = (const float*)d_in[8];
    const float* eWhhB   = (const float*)d_in[9];
    const float* ebB     = (const float*)d_in[10];
    const float* dWih    = (const float*)d_in[11];
    const float* dWhh    = (const float*)d_in[12];
    const float* db      = (const float*)d_in[13];
    const float* Wasrc   = (const float*)d_in[14];
    const float* Wavec   = (const float*)d_in[15];
    const float* Wread   = (const float*)d_in[16];
    const float* Winit   = (const float*)d_in[17];
    const float* binit   = (const float*)d_in[18];
    float* ws  = (float*)d_ws;
    float* out = (float*)d_out;

    float* senc = ws + o_senc;  float* satt = ws + o_satt; float* aves = ws + o_aves;
    float* hF = ws + o_hF; float* cF = ws + o_cF; float* hB = ws + o_hB; float* cB = ws + o_cB;
    float* sumexp = ws + o_sumexp; float* gold = ws + o_gold;
    float* ccat = ws + o_ccat;
    float* dech = ws + o_dech; float* decc = ws + o_decc;
    float* ctx = ws + o_ctx;
    float* gatesP = ws + o_gatesP; float* attvP = ws + o_attvP;

    // device-symbol pointers
    float* Xf; short *WreadBf, *srcxBf, *tgtyBf, *WihFbf, *WihBbf, *dWihYbf;
    hipGetSymbolAddress((void**)&Xf, HIP_SYMBOL(g_X));
    hipGetSymbolAddress((void**)&WreadBf, HIP_SYMBOL(g_Wread_bf));
    hipGetSymbolAddress((void**)&srcxBf, HIP_SYMBOL(g_bfA));
    hipGetSymbolAddress((void**)&WihFbf, HIP_SYMBOL(g_bfW));
    tgtyBf = srcxBf + 2048L*512;
    WihBbf = WihFbf + 2048L*512;
    dWihYbf = WihFbf + 2L*2048*512;
    float* Xb = Xf + 2048L*2048;
    float* Yg = Xf + 2L*2048*2048;

    // zero states + sumexp
    k_zero<<<264, 256, 0, stream>>>(hF, 67584);

    // bf16 conversions + gathers
    k_cvt<<<4096, 256, 0, stream>>>(eWihF, WihFbf, 512);
    k_cvt<<<4096, 256, 0, stream>>>(eWihB, WihBbf, 512);
    k_cvt<<<4096, 256, 0, stream>>>(dWih, dWihYbf, 1024);   // cols 0..511
    k_cvt<<<64000, 256, 0, stream>>>(Wread, WreadBf, 512);
    k_gather_bf<<<4096, 256, 0, stream>>>(src_emb, src_tok, srcxBf, 0);
    k_gather_bf<<<4096, 256, 0, stream>>>(tgt_emb, tgt_tok, tgtyBf, 1);

    // x-part precompute: Xf, Xb, Yg = emb x Wih^T (MFMA)
    k_mfma_gemm<1><<<dim3(16,16), 256, 0, stream>>>(srcxBf, WihFbf, Xf, 2048);
    k_mfma_gemm<1><<<dim3(16,16), 256, 0, stream>>>(srcxBf, WihBbf, Xb, 2048);
    k_mfma_gemm<1><<<dim3(16,16), 256, 0, stream>>>(tgtyBf, dWihYbf, Yg, 2048);

    // encoder recurrence (h-part only per step)
    for (int s = 0; s < 64; ++s){
        k_enc_gates<<<256, 256, 0, stream>>>(hF, hB, eWhhF, eWhhB, gatesP);
        k_enc_cell<<<128, 256, 0, stream>>>(gatesP, ebF, ebB, hF, cF, hB, cB, senc, lens, s);
    }

    // [c_f|c_b]; src_att; decoder init
    k_ccat<<<128, 256, 0, stream>>>(cF, cB, ccat);
    k_gemm<<<dim3(32,8), 256, 0, stream>>>(senc, Wasrc, nullptr, satt, 2048, 1024, 1024, 1024, 512);
    k_gemm<<<dim3(1,8), 256, 0, stream>>>(ccat, Winit, binit, decc, 32, 1024, 1024, 1024, 512);
    k_dec_init<<<64, 256, 0, stream>>>(decc, dech);

    // decoder recurrence: 3 kernels/step (fin folded into gates)
    for (int t = 0; t < 64; ++t){
        k_dec_gates<<<320, 256, 0, stream>>>(dech, dWih, dWhh, attvP, gatesP, aves, t);
        k_dec_attn<<<32, 256, 0, stream>>>(gatesP, db, dech, decc, satt, senc, lens, ctx, t);
        k_attvec<<<96, 256, 0, stream>>>(dech, ctx, Wavec, attvP);
    }
    k_aves_last<<<64, 256, 0, stream>>>(attvP, aves);

    // readout: MFMA bf16 GEMM with fused exp-sum; gold; final
    short* avesBf; hipGetSymbolAddress((void**)&avesBf, HIP_SYMBOL(g_aves_bf));
    k_mfma_gemm<0><<<dim3(16,250), 256, 0, stream>>>(avesBf, WreadBf, sumexp, 0);
    k_gold<<<512, 256, 0, stream>>>(aves, Wread, tgt_tok, gold);
    k_final<<<1, 64, 0, stream>>>(gold, sumexp, tgt_tok, out);
}